// Round 2
// 343.139 us; speedup vs baseline: 1.0325x; 1.0325x over previous
//
#include <hip/hip_runtime.h>
#include <cstdint>
#include <cstddef>

#define BB 4
#define LL 2048
#define EE 1024
#define HH 16
#define DD 64
#define TT (BB*LL)      // 8192 tokens
#define EPSF 1e-5f

typedef _Float16 half8 __attribute__((ext_vector_type(8)));
typedef _Float16 half4v __attribute__((ext_vector_type(4)));
typedef float floatx4 __attribute__((ext_vector_type(4)));
typedef float floatx16 __attribute__((ext_vector_type(16)));
typedef int intx4 __attribute__((ext_vector_type(4)));
typedef unsigned int uintx4 __attribute__((ext_vector_type(4)));
typedef unsigned int uint2v __attribute__((ext_vector_type(2)));

__device__ __forceinline__ void gl_lds16(const void* g, void* l) {
    __builtin_amdgcn_global_load_lds(
        (const __attribute__((address_space(1))) void*)g,
        (__attribute__((address_space(3))) void*)l, 16, 0, 0);
}

// pack two fp32 -> two f16 (rtne) in one u32
__device__ __forceinline__ uint32_t pk2(float a, float b) {
    union { _Float16 h[2]; uint32_t u; } x;
    x.h[0] = (_Float16)a; x.h[1] = (_Float16)b;
    return x.u;
}

// ---------------- kernel 1: per-tensor abs-sum (fp64 for determinism) ----------------
__global__ void k_absum(const float* __restrict__ in_proj,
                        const float* __restrict__ out_proj,
                        double* __restrict__ sums) {
    const int which = blockIdx.y;  // 0=q,1=k,2=v,3=o
    const float* src = (which < 3) ? (in_proj + (size_t)which * EE * EE) : out_proj;
    double loc = 0.0;
    const int n = EE * EE;
    for (int i = blockIdx.x * blockDim.x + threadIdx.x; i < n; i += gridDim.x * blockDim.x)
        loc += (double)fabsf(src[i]);
    #pragma unroll
    for (int off = 32; off > 0; off >>= 1) loc += __shfl_down(loc, off, 64);
    __shared__ double red[4];
    const int lane = threadIdx.x & 63, wv = threadIdx.x >> 6;
    if (lane == 0) red[wv] = loc;
    __syncthreads();
    if (threadIdx.x == 0) {
        double tot = red[0] + red[1] + red[2] + red[3];
        atomicAdd(&sums[which], tot);
    }
}

// ---------------- kernel 2: ternarize weights -> int8 {-1,0,1} ----------------
__global__ void k_quantw(const float* __restrict__ in_proj,
                         const float* __restrict__ out_proj,
                         const double* __restrict__ sums,
                         float* __restrict__ scaleF,
                         int8_t* __restrict__ qw) {
    const int idx = blockIdx.x * blockDim.x + threadIdx.x;  // exactly 4M threads
    if (idx < 4) scaleF[idx] = fmaxf((float)(sums[idx] * (1.0 / (EE * EE))), EPSF);
    const int which = idx >> 20;  // /(EE*EE)
    const float s = fmaxf((float)(sums[which] * (1.0 / (EE * EE))), EPSF);
    const float w = (which < 3) ? in_proj[idx] : out_proj[idx - 3 * EE * EE];
    float q = rintf(w / s);            // round-half-even, matches jnp.round
    q = fminf(fmaxf(q, -1.f), 1.f);
    qw[idx] = (int8_t)q;
}

// ---------------- gamma + int8 activation quantization (device body) ----------------
__device__ __forceinline__ void gammaq_body(const float* __restrict__ x,
                                            float* __restrict__ g,
                                            int8_t* __restrict__ qx) {
    const int wv = threadIdx.x >> 6, lane = threadIdx.x & 63;
    const int tok = blockIdx.x * 4 + wv;
    const float* xp = x + (size_t)tok * EE;
    float4 v[4];
    #pragma unroll
    for (int i = 0; i < 4; i++) v[i] = *(const float4*)(xp + (lane + 64 * i) * 4);
    float m = 0.f;
    #pragma unroll
    for (int i = 0; i < 4; i++)
        m = fmaxf(m, fmaxf(fmaxf(fabsf(v[i].x), fabsf(v[i].y)),
                           fmaxf(fabsf(v[i].z), fabsf(v[i].w))));
    #pragma unroll
    for (int off = 1; off < 64; off <<= 1) m = fmaxf(m, __shfl_xor(m, off, 64));
    const float gg = fmaxf(m, EPSF);
    const float rg = 128.f / gg;     // matches reference x * (q/gamma)
    int8_t* qp = qx + (size_t)tok * EE;
    #pragma unroll
    for (int i = 0; i < 4; i++) {
        char4 c;
        c.x = (int8_t)(int)fminf(fmaxf(rintf(v[i].x * rg), -128.f), 127.f);
        c.y = (int8_t)(int)fminf(fmaxf(rintf(v[i].y * rg), -128.f), 127.f);
        c.z = (int8_t)(int)fminf(fmaxf(rintf(v[i].z * rg), -128.f), 127.f);
        c.w = (int8_t)(int)fminf(fmaxf(rintf(v[i].w * rg), -128.f), 127.f);
        *(char4*)(qp + (lane + 64 * i) * 4) = c;
    }
    if (lane == 0) g[tok] = gg;
}

// merged q/k/v quantization: blockIdx.y selects tensor
__global__ __launch_bounds__(256) void k_gammaq3(const float* __restrict__ q,
                                                 const float* __restrict__ k,
                                                 const float* __restrict__ v,
                                                 float* __restrict__ g,
                                                 int8_t* __restrict__ qx) {
    const int y = blockIdx.y;
    const float* src = (y == 0) ? q : (y == 1) ? k : v;
    gammaq_body(src, g + (size_t)y * TT, qx + (size_t)y * TT * EE);
}

__global__ __launch_bounds__(256) void k_gammaq(const float* __restrict__ x,
                                                float* __restrict__ g,
                                                int8_t* __restrict__ qx) {
    gammaq_body(x, g, qx);
}

// ---------------- BitLinear via i8 MFMA (exact i32 integer arithmetic) ---------------
// block 128(t) x 128(o), BK=128, 4 waves 2x2, wave tile 64x64 (4x4 of 16x16x64 i8).
// LDS rows of 128 i8 = 8 x 16B chunks; logical chunk c of row R stored at phys
// c ^ (R&7) ^ ((R>>3)&7)  (full 3-term swizzle -> conflict-free frag reads).
// widx = wbase + blockIdx.z selects weight/activation slab and epilogue:
//   widx 0: f16 [B,H,L,D] * qpre (Q)   widx 1: f16 [B,H,L,D] (K)
//   widx 2: f16 V^T [B,H,D,L] via LDS transpose   widx 3: fp32 [T,E] (out-proj)
__global__ __launch_bounds__(256) void k_bitmm(
    const int8_t* __restrict__ qx_all, const float* __restrict__ gam_all,
    const int8_t* __restrict__ qw_all, const float* __restrict__ scaleF,
    const float* __restrict__ in_proj_b, const float* __restrict__ out_proj_b,
    float* __restrict__ outF, _Float16* __restrict__ outH_all,
    int wbase, float qpre) {
    __shared__ __align__(16) int8_t smem[36864];
    int8_t (*As)[128] = (int8_t(*)[128])smem;
    int8_t (*Bs)[128] = (int8_t(*)[128])(smem + 16384);
    _Float16 (*Vt)[136] = (_Float16(*)[136])smem;   // mode-2 reuse after sync
    const int widx = wbase + blockIdx.z;
    const int8_t* qx = qx_all + (size_t)widx * TT * EE;
    const int8_t* qw = qw_all + (size_t)widx * EE * EE;
    const float* gam = gam_all + (size_t)widx * TT;
    const float* bias = (widx < 3) ? (in_proj_b + widx * EE) : out_proj_b;
    _Float16* outH = outH_all + (size_t)widx * TT * EE;   // slabs Q,K,Vt
    const float pre = (widx == 0) ? qpre : 1.0f;
    const int tid = threadIdx.x;
    const int wv = tid >> 6, lane = tid & 63;
    const int quad = lane >> 4, l16 = lane & 15;
    const int wm = wv & 1, wn = wv >> 1;
    const int t0 = blockIdx.x * 128, o0 = blockIdx.y * 128;
    const int srow = lane >> 3, schunk = lane & 7;

    intx4 acc[4][4];
    #pragma unroll
    for (int i = 0; i < 4; i++)
        #pragma unroll
        for (int j = 0; j < 4; j++) acc[i][j] = (intx4){0, 0, 0, 0};

    for (int k0 = 0; k0 < EE; k0 += 128) {
        __syncthreads();
        #pragma unroll
        for (int p = 0; p < 4; p++) {
            const int g = wv * 4 + p;                    // row-group 0..15
            const int c = schunk ^ srow ^ (g & 7);       // logical chunk
            const int row = g * 8 + srow;
            gl_lds16(qx + (size_t)(t0 + row) * EE + k0 + c * 16, &As[g * 8][0]);
            gl_lds16(qw + (size_t)(o0 + row) * EE + k0 + c * 16, &Bs[g * 8][0]);
        }
        __syncthreads();
        #pragma unroll
        for (int kk = 0; kk < 2; kk++) {
            intx4 af[4], bf[4];
            #pragma unroll
            for (int s4 = 0; s4 < 4; s4++) {
                const int mR = (l16 & 7) ^ ((s4 * 2 + (l16 >> 3)) & 7);
                const int ph = ((kk * 4 + quad) ^ mR) * 16;
                af[s4] = *(const intx4*)&As[wm * 64 + s4 * 16 + l16][ph];
                bf[s4] = *(const intx4*)&Bs[wn * 64 + s4 * 16 + l16][ph];
            }
            #pragma unroll
            for (int sm = 0; sm < 4; sm++)
                #pragma unroll
                for (int sn = 0; sn < 4; sn++)
                    acc[sm][sn] = __builtin_amdgcn_mfma_i32_16x16x64_i8(
                        af[sm], bf[sn], acc[sm][sn], 0, 0, 0);
        }
    }

    const float s = scaleF[widx];
    if (widx == 2) {
        // V^T: stage f16 into LDS [o][t] then coalesced store along t (=L)
        __syncthreads();
        #pragma unroll
        for (int sm = 0; sm < 4; sm++) {
            const int tl = wm * 64 + sm * 16 + quad * 4;
            float mr[4];
            #pragma unroll
            for (int r = 0; r < 4; r++) mr[r] = s * gam[t0 + tl + r] * 0.0078125f;
            #pragma unroll
            for (int sn = 0; sn < 4; sn++) {
                const int ol = wn * 64 + sn * 16 + l16;
                const float b = bias[o0 + ol];
                half4v hv;
                #pragma unroll
                for (int r = 0; r < 4; r++)
                    hv[r] = (_Float16)((float)acc[sm][sn][r] * mr[r] + b);
                *(half4v*)&Vt[ol][tl] = hv;
            }
        }
        __syncthreads();
        const int ol2 = tid >> 1, tc0 = (tid & 1) * 64;
        const int og = o0 + ol2, hh = og >> 6, dd = og & 63;
        const int bb = t0 >> 11, l0 = t0 & (LL - 1);
        _Float16* dst = outH + ((size_t)(bb * HH + hh) * DD + dd) * LL + l0 + tc0;
        #pragma unroll
        for (int i = 0; i < 8; i++)
            *(half8*)(dst + i * 8) = *(const half8*)&Vt[ol2][tc0 + i * 8];
        return;
    }
    #pragma unroll
    for (int sm = 0; sm < 4; sm++) {
        #pragma unroll
        for (int r = 0; r < 4; r++) {
            const int t = t0 + wm * 64 + sm * 16 + quad * 4 + r;
            const float mr = s * gam[t] * 0.0078125f;   // s*g/128
            const int b_ = t >> 11, l_ = t & (LL - 1);
            #pragma unroll
            for (int sn = 0; sn < 4; sn++) {
                const int o = o0 + wn * 64 + sn * 16 + l16;
                const float val = (float)acc[sm][sn][r] * mr + bias[o];
                if (widx == 3) {
                    outF[(size_t)t * EE + o] = val;
                } else {  // f16 [B,H,L,D] (Q with pre, K)
                    const int h_ = o >> 6, d_ = o & 63;
                    outH[((size_t)(b_ * HH + h_) * LL + l_) * DD + d_] = (_Float16)(val * pre);
                }
            }
        }
    }
}

// ---------------- MFMA 32x32 flash attention, 32q/wave, register-P -------------------
// Block = 4 waves = 128 q. S^T = K.Q^T (A=K from LDS, B=Q regs). P transposed
// C->A layout in registers via permlane32_swap (q = lane&31 in both halves).
// ctx = P.V^T. Fixed-max exp2 softmax. Full 3-term XOR swizzle on K and V^T.
// 2-phase double-buffered K/V staging: prefetch tile t+1 BEFORE computing tile t;
// one __syncthreads() per iter (stage latency hides under MFMA + softmax).
__global__ __launch_bounds__(256, 4) void k_attn5(const _Float16* __restrict__ Q,
                                                  const _Float16* __restrict__ K,
                                                  const _Float16* __restrict__ Vt,
                                                  float* __restrict__ ctx) {
    __shared__ __align__(16) _Float16 Ksh[2][64][64];    // [buf][key][d]
    __shared__ __align__(16) _Float16 Vtsh[2][64][64];   // [buf][d][key]
    const int tid = threadIdx.x;
    const int wv = tid >> 6, lane = tid & 63;
    const int l32 = lane & 31, h2 = lane >> 5;
    const int bh = blockIdx.y, b_ = bh >> 4, h_ = bh & 15;
    const int q0 = blockIdx.x * 128 + wv * 32;
    const int srow = lane >> 3, schunk = lane & 7;

    const _Float16* Qb = Q + (size_t)bh * LL * DD;
    const _Float16* Kb = K + (size_t)bh * LL * DD;
    const _Float16* Vtb = Vt + (size_t)bh * DD * LL;

    // Q B-frags: B[n=q=l32][k=d=ds*16+8*h2+j]; Q pre-scaled by 0.125*log2e
    half8 qf[4];
    #pragma unroll
    for (int ds = 0; ds < 4; ds++)
        qf[ds] = *(const half8*)(Qb + (size_t)(q0 + l32) * DD + ds * 16 + h2 * 8);

    floatx16 acc[2];
    #pragma unroll
    for (int r = 0; r < 16; r++) { acc[0][r] = 0.f; acc[1][r] = 0.f; }
    float lsum = 0.f;

    // prologue: stage tile 0 into buf 0
    {
        #pragma unroll
        for (int u = 0; u < 2; u++) {
            const int g = wv * 2 + u;                    // row-group 0..7
            const int c = schunk ^ srow ^ (g & 7);       // logical chunk
            const int row = g * 8 + srow;
            gl_lds16(Kb + (size_t)row * DD + c * 8, &Ksh[0][g * 8][0]);
            gl_lds16(Vtb + (size_t)row * LL + c * 8, &Vtsh[0][g * 8][0]);
        }
    }
    __syncthreads();

    for (int kt = 0; kt < LL; kt += 64) {
        const int cur = (kt >> 6) & 1;

        // issue next-tile stage into buf cur^1 (latency hides under compute)
        if (kt + 64 < LL) {
            const int nkt = kt + 64;
            #pragma unroll
            for (int u = 0; u < 2; u++) {
                const int g = wv * 2 + u;
                const int c = schunk ^ srow ^ (g & 7);
                const int row = g * 8 + srow;
                gl_lds16(Kb + (size_t)(nkt + row) * DD + c * 8, &Ksh[cur ^ 1][g * 8][0]);
                gl_lds16(Vtb + (size_t)row * LL + nkt + c * 8, &Vtsh[cur ^ 1][g * 8][0]);
            }
        }

        // ---- S^T + exp2 + register transpose to A-layout P ----
        half8 pa[4];
        #pragma unroll
        for (int ks = 0; ks < 2; ks++) {
            const int rowK = ks * 32 + l32;
            const int mK = (l32 & 7) ^ ((ks * 4 + (l32 >> 3)) & 7);
            floatx16 sc;
            #pragma unroll
            for (int r = 0; r < 16; r++) sc[r] = 0.f;
            __builtin_amdgcn_s_setprio(1);
            #pragma unroll
            for (int ds = 0; ds < 4; ds++) {
                const half8 kf = *(const half8*)&Ksh[cur][rowK][((2 * ds + h2) ^ mK) * 8];
                sc = __builtin_amdgcn_mfma_f32_32x32x16_f16(kf, qf[ds], sc, 0, 0, 0);
            }
            __builtin_amdgcn_s_setprio(0);
            // lane holds keys ks*32 + 8*c4 + 4*h2 + j  for q = l32
            float p[16];
            #pragma unroll
            for (int r = 0; r < 16; r++) p[r] = __builtin_amdgcn_exp2f(sc[r]);
            #pragma unroll
            for (int r = 0; r < 16; r++) lsum += p[r];
            uint32_t u_[4][2];
            #pragma unroll
            for (int c4 = 0; c4 < 4; c4++) {
                u_[c4][0] = pk2(p[4 * c4 + 0], p[4 * c4 + 1]);
                u_[c4][1] = pk2(p[4 * c4 + 2], p[4 * c4 + 3]);
            }
            // A-frag words for kb = ks*2+mm: keys kb*16 + h2*8 + {0..7}.
            // permlane32_swap(A,B): ret0 = {A.lo-half, B.lo-half},
            //                       ret1 = {A.hi-half, B.hi-half} (per lane-half)
            #pragma unroll
            for (int mm = 0; mm < 2; mm++) {
                uint2v s0 = __builtin_amdgcn_permlane32_swap(
                    u_[2 * mm][0], u_[2 * mm + 1][0], false, false);
                uint2v s1 = __builtin_amdgcn_permlane32_swap(
                    u_[2 * mm][1], u_[2 * mm + 1][1], false, false);
                uintx4 w;
                w[0] = s0[0]; w[1] = s1[0]; w[2] = s0[1]; w[3] = s1[1];
                union { uintx4 u; half8 h; } cv; cv.u = w;
                pa[ks * 2 + mm] = cv.h;
            }
        }

        // ---- ctx += P . V^T ----
        __builtin_amdgcn_s_setprio(1);
        #pragma unroll
        for (int kb = 0; kb < 4; kb++) {
            #pragma unroll
            for (int sd = 0; sd < 2; sd++) {
                const int rowV = sd * 32 + l32;
                const int mV = (l32 & 7) ^ ((sd * 4 + (l32 >> 3)) & 7);
                const half8 vf = *(const half8*)&Vtsh[cur][rowV][((2 * kb + h2) ^ mV) * 8];
                acc[sd] = __builtin_amdgcn_mfma_f32_32x32x16_f16(pa[kb], vf, acc[sd], 0, 0, 0);
            }
        }
        __builtin_amdgcn_s_setprio(0);

        // drain own prefetch (vmcnt) + all waves done reading buf cur
        __syncthreads();
    }

    // ---- epilogue: ctx [B, L, E] fp32 ----
    lsum += __shfl_xor(lsum, 32, 64);
    const float invl = 1.f / lsum;
    #pragma unroll
    for (int r = 0; r < 16; r++) {
        const int qrow = (r & 3) + 8 * (r >> 2) + 4 * h2;
        const float iv = __shfl(invl, qrow, 64);
        float* cp = ctx + ((size_t)b_ * LL + q0 + qrow) * EE + h_ * DD + l32;
        cp[0]  = acc[0][r] * iv;
        cp[32] = acc[1][r] * iv;
    }
}

// ---------------- launcher ----------------
extern "C" void kernel_launch(void* const* d_in, const int* in_sizes, int n_in,
                              void* d_out, int out_size, void* d_ws, size_t ws_size,
                              hipStream_t stream) {
    const float* query      = (const float*)d_in[0];
    const float* key        = (const float*)d_in[1];
    const float* value      = (const float*)d_in[2];
    const float* in_proj_w  = (const float*)d_in[3];
    const float* in_proj_b  = (const float*)d_in[4];
    const float* out_proj_w = (const float*)d_in[5];
    const float* out_proj_b = (const float*)d_in[6];
    float* out = (float*)d_out;

    char* ws = (char*)d_ws;
    double*   sums   = (double*)ws;                             // 32 B
    float*    scaleF = (float*)(ws + 32);                       // 16 B
    float*    gbuf   = (float*)(ws + 256);                      // 4*TT floats
    int8_t*   qw8    = (int8_t*)(ws + (size_t)1  * 1024 * 1024);  // 4 MB ternary i8
    int8_t*   qx8    = (int8_t*)(ws + (size_t)8  * 1024 * 1024);  // 4 slabs x 8 MB
    _Float16* Qh     = (_Float16*)(ws + (size_t)40 * 1024 * 1024); // 3 slabs x 16 MB
    _Float16* Kh     = Qh + (size_t)TT * EE;
    _Float16* Vth    = Kh + (size_t)TT * EE;                    // V^T [B,H,D,L]
    float*    ctx    = out;   // d_out doubles as fp32 ctx scratch (fully overwritten)

    const float QPRE = 0.18033688011112042f;  // (1/8) * log2(e)

    hipMemsetAsync(sums, 0, 32, stream);
    k_absum<<<dim3(64, 4), 256, 0, stream>>>(in_proj_w, out_proj_w, sums);
    k_quantw<<<(4 * EE * EE) / 256, 256, 0, stream>>>(in_proj_w, out_proj_w, sums, scaleF, qw8);
    k_gammaq3<<<dim3(TT / 4, 3), 256, 0, stream>>>(query, key, value, gbuf, qx8);

    // fused Q/K/V^T projections (widx = blockIdx.z)
    k_bitmm<<<dim3(TT / 128, EE / 128, 3), 256, 0, stream>>>(
        qx8, gbuf, qw8, scaleF, in_proj_b, out_proj_b, nullptr, Qh, 0, QPRE);

    k_attn5<<<dim3(LL / 128, BB * HH), 256, 0, stream>>>(Qh, Kh, Vth, ctx);

    // requantize ctx (slab 3) + out-projection
    k_gammaq<<<TT / 4, 256, 0, stream>>>(ctx, gbuf + 3 * TT, qx8 + 3 * (size_t)TT * EE);
    k_bitmm<<<dim3(TT / 128, EE / 128, 1), 256, 0, stream>>>(
        qx8, gbuf, qw8, scaleF, in_proj_b, out_proj_b, out, Qh, 3, QPRE);
}

// Round 4
// 340.483 us; speedup vs baseline: 1.0406x; 1.0078x over previous
//
#include <hip/hip_runtime.h>
#include <cstdint>
#include <cstddef>

#define BB 4
#define LL 2048
#define EE 1024
#define HH 16
#define DD 64
#define TT (BB*LL)      // 8192 tokens
#define EPSF 1e-5f

typedef _Float16 half8 __attribute__((ext_vector_type(8)));
typedef _Float16 half4v __attribute__((ext_vector_type(4)));
typedef float floatx4 __attribute__((ext_vector_type(4)));
typedef float floatx16 __attribute__((ext_vector_type(16)));
typedef int intx4 __attribute__((ext_vector_type(4)));
typedef unsigned int uintx4 __attribute__((ext_vector_type(4)));
typedef unsigned int uint2v __attribute__((ext_vector_type(2)));

__device__ __forceinline__ void gl_lds16(const void* g, void* l) {
    __builtin_amdgcn_global_load_lds(
        (const __attribute__((address_space(1))) void*)g,
        (__attribute__((address_space(3))) void*)l, 16, 0, 0);
}

// pack two fp32 -> two f16 (rtne) in one u32
__device__ __forceinline__ uint32_t pk2(float a, float b) {
    union { _Float16 h[2]; uint32_t u; } x;
    x.h[0] = (_Float16)a; x.h[1] = (_Float16)b;
    return x.u;
}

// pack two fp32 -> two f16 (rtz, single VALU op v_cvt_pkrtz_f16_f32)
__device__ __forceinline__ uint32_t pkrtz(float a, float b) {
    return __builtin_bit_cast(uint32_t, __builtin_amdgcn_cvt_pkrtz(a, b));
}

// ---------------- kernel 1: per-tensor abs-sum (fp64 for determinism) ----------------
__global__ void k_absum(const float* __restrict__ in_proj,
                        const float* __restrict__ out_proj,
                        double* __restrict__ sums) {
    const int which = blockIdx.y;  // 0=q,1=k,2=v,3=o
    const float* src = (which < 3) ? (in_proj + (size_t)which * EE * EE) : out_proj;
    double loc = 0.0;
    const int n = EE * EE;
    for (int i = blockIdx.x * blockDim.x + threadIdx.x; i < n; i += gridDim.x * blockDim.x)
        loc += (double)fabsf(src[i]);
    #pragma unroll
    for (int off = 32; off > 0; off >>= 1) loc += __shfl_down(loc, off, 64);
    __shared__ double red[4];
    const int lane = threadIdx.x & 63, wv = threadIdx.x >> 6;
    if (lane == 0) red[wv] = loc;
    __syncthreads();
    if (threadIdx.x == 0) {
        double tot = red[0] + red[1] + red[2] + red[3];
        atomicAdd(&sums[which], tot);
    }
}

// ---------------- kernel 2: ternarize weights -> int8 {-1,0,1} ----------------
__global__ void k_quantw(const float* __restrict__ in_proj,
                         const float* __restrict__ out_proj,
                         const double* __restrict__ sums,
                         float* __restrict__ scaleF,
                         int8_t* __restrict__ qw) {
    const int idx = blockIdx.x * blockDim.x + threadIdx.x;  // exactly 4M threads
    if (idx < 4) scaleF[idx] = fmaxf((float)(sums[idx] * (1.0 / (EE * EE))), EPSF);
    const int which = idx >> 20;  // /(EE*EE)
    const float s = fmaxf((float)(sums[which] * (1.0 / (EE * EE))), EPSF);
    const float w = (which < 3) ? in_proj[idx] : out_proj[idx - 3 * EE * EE];
    float q = rintf(w / s);            // round-half-even, matches jnp.round
    q = fminf(fmaxf(q, -1.f), 1.f);
    qw[idx] = (int8_t)q;
}

// ---------------- gamma + int8 activation quantization (device body) ----------------
__device__ __forceinline__ void gammaq_body(const float* __restrict__ x,
                                            float* __restrict__ g,
                                            int8_t* __restrict__ qx) {
    const int wv = threadIdx.x >> 6, lane = threadIdx.x & 63;
    const int tok = blockIdx.x * 4 + wv;
    const float* xp = x + (size_t)tok * EE;
    float4 v[4];
    #pragma unroll
    for (int i = 0; i < 4; i++) v[i] = *(const float4*)(xp + (lane + 64 * i) * 4);
    float m = 0.f;
    #pragma unroll
    for (int i = 0; i < 4; i++)
        m = fmaxf(m, fmaxf(fmaxf(fabsf(v[i].x), fabsf(v[i].y)),
                           fmaxf(fabsf(v[i].z), fabsf(v[i].w))));
    #pragma unroll
    for (int off = 1; off < 64; off <<= 1) m = fmaxf(m, __shfl_xor(m, off, 64));
    const float gg = fmaxf(m, EPSF);
    const float rg = 128.f / gg;     // matches reference x * (q/gamma)
    int8_t* qp = qx + (size_t)tok * EE;
    #pragma unroll
    for (int i = 0; i < 4; i++) {
        char4 c;
        c.x = (int8_t)(int)fminf(fmaxf(rintf(v[i].x * rg), -128.f), 127.f);
        c.y = (int8_t)(int)fminf(fmaxf(rintf(v[i].y * rg), -128.f), 127.f);
        c.z = (int8_t)(int)fminf(fmaxf(rintf(v[i].z * rg), -128.f), 127.f);
        c.w = (int8_t)(int)fminf(fmaxf(rintf(v[i].w * rg), -128.f), 127.f);
        *(char4*)(qp + (lane + 64 * i) * 4) = c;
    }
    if (lane == 0) g[tok] = gg;
}

// merged q/k/v quantization: blockIdx.y selects tensor
__global__ __launch_bounds__(256) void k_gammaq3(const float* __restrict__ q,
                                                 const float* __restrict__ k,
                                                 const float* __restrict__ v,
                                                 float* __restrict__ g,
                                                 int8_t* __restrict__ qx) {
    const int y = blockIdx.y;
    const float* src = (y == 0) ? q : (y == 1) ? k : v;
    gammaq_body(src, g + (size_t)y * TT, qx + (size_t)y * TT * EE);
}

__global__ __launch_bounds__(256) void k_gammaq(const float* __restrict__ x,
                                                float* __restrict__ g,
                                                int8_t* __restrict__ qx) {
    gammaq_body(x, g, qx);
}

// ---------------- BitLinear via i8 MFMA (exact i32 integer arithmetic) ---------------
// block 128(t) x 128(o), BK=128, 4 waves 2x2, wave tile 64x64 (4x4 of 16x16x64 i8).
// LDS rows of 128 i8 = 8 x 16B chunks; logical chunk c of row R stored at phys
// c ^ (R&7) ^ ((R>>3)&7)  (full 3-term swizzle -> conflict-free frag reads).
// widx = wbase + blockIdx.z selects weight/activation slab and epilogue:
//   widx 0: f16 [B,H,L,D] * qpre (Q)   widx 1: f16 [B,H,L,D] (K)
//   widx 2: f16 V^T [B,H,D,L] via LDS transpose   widx 3: fp32 [T,E] (out-proj)
__global__ __launch_bounds__(256) void k_bitmm(
    const int8_t* __restrict__ qx_all, const float* __restrict__ gam_all,
    const int8_t* __restrict__ qw_all, const float* __restrict__ scaleF,
    const float* __restrict__ in_proj_b, const float* __restrict__ out_proj_b,
    float* __restrict__ outF, _Float16* __restrict__ outH_all,
    int wbase, float qpre) {
    __shared__ __align__(16) int8_t smem[36864];
    int8_t (*As)[128] = (int8_t(*)[128])smem;
    int8_t (*Bs)[128] = (int8_t(*)[128])(smem + 16384);
    _Float16 (*Vt)[136] = (_Float16(*)[136])smem;   // mode-2 reuse after sync
    const int widx = wbase + blockIdx.z;
    const int8_t* qx = qx_all + (size_t)widx * TT * EE;
    const int8_t* qw = qw_all + (size_t)widx * EE * EE;
    const float* gam = gam_all + (size_t)widx * TT;
    const float* bias = (widx < 3) ? (in_proj_b + widx * EE) : out_proj_b;
    _Float16* outH = outH_all + (size_t)widx * TT * EE;   // slabs Q,K,Vt
    const float pre = (widx == 0) ? qpre : 1.0f;
    const int tid = threadIdx.x;
    const int wv = tid >> 6, lane = tid & 63;
    const int quad = lane >> 4, l16 = lane & 15;
    const int wm = wv & 1, wn = wv >> 1;
    const int t0 = blockIdx.x * 128, o0 = blockIdx.y * 128;
    const int srow = lane >> 3, schunk = lane & 7;

    intx4 acc[4][4];
    #pragma unroll
    for (int i = 0; i < 4; i++)
        #pragma unroll
        for (int j = 0; j < 4; j++) acc[i][j] = (intx4){0, 0, 0, 0};

    for (int k0 = 0; k0 < EE; k0 += 128) {
        __syncthreads();
        #pragma unroll
        for (int p = 0; p < 4; p++) {
            const int g = wv * 4 + p;                    // row-group 0..15
            const int c = schunk ^ srow ^ (g & 7);       // logical chunk
            const int row = g * 8 + srow;
            gl_lds16(qx + (size_t)(t0 + row) * EE + k0 + c * 16, &As[g * 8][0]);
            gl_lds16(qw + (size_t)(o0 + row) * EE + k0 + c * 16, &Bs[g * 8][0]);
        }
        __syncthreads();
        #pragma unroll
        for (int kk = 0; kk < 2; kk++) {
            intx4 af[4], bf[4];
            #pragma unroll
            for (int s4 = 0; s4 < 4; s4++) {
                const int mR = (l16 & 7) ^ ((s4 * 2 + (l16 >> 3)) & 7);
                const int ph = ((kk * 4 + quad) ^ mR) * 16;
                af[s4] = *(const intx4*)&As[wm * 64 + s4 * 16 + l16][ph];
                bf[s4] = *(const intx4*)&Bs[wn * 64 + s4 * 16 + l16][ph];
            }
            #pragma unroll
            for (int sm = 0; sm < 4; sm++)
                #pragma unroll
                for (int sn = 0; sn < 4; sn++)
                    acc[sm][sn] = __builtin_amdgcn_mfma_i32_16x16x64_i8(
                        af[sm], bf[sn], acc[sm][sn], 0, 0, 0);
        }
    }

    const float s = scaleF[widx];
    if (widx == 2) {
        // V^T: stage f16 into LDS [o][t] then coalesced store along t (=L)
        __syncthreads();
        #pragma unroll
        for (int sm = 0; sm < 4; sm++) {
            const int tl = wm * 64 + sm * 16 + quad * 4;
            float mr[4];
            #pragma unroll
            for (int r = 0; r < 4; r++) mr[r] = s * gam[t0 + tl + r] * 0.0078125f;
            #pragma unroll
            for (int sn = 0; sn < 4; sn++) {
                const int ol = wn * 64 + sn * 16 + l16;
                const float b = bias[o0 + ol];
                half4v hv;
                #pragma unroll
                for (int r = 0; r < 4; r++)
                    hv[r] = (_Float16)((float)acc[sm][sn][r] * mr[r] + b);
                *(half4v*)&Vt[ol][tl] = hv;
            }
        }
        __syncthreads();
        const int ol2 = tid >> 1, tc0 = (tid & 1) * 64;
        const int og = o0 + ol2, hh = og >> 6, dd = og & 63;
        const int bb = t0 >> 11, l0 = t0 & (LL - 1);
        _Float16* dst = outH + ((size_t)(bb * HH + hh) * DD + dd) * LL + l0 + tc0;
        #pragma unroll
        for (int i = 0; i < 8; i++)
            *(half8*)(dst + i * 8) = *(const half8*)&Vt[ol2][tc0 + i * 8];
        return;
    }
    #pragma unroll
    for (int sm = 0; sm < 4; sm++) {
        #pragma unroll
        for (int r = 0; r < 4; r++) {
            const int t = t0 + wm * 64 + sm * 16 + quad * 4 + r;
            const float mr = s * gam[t] * 0.0078125f;   // s*g/128
            const int b_ = t >> 11, l_ = t & (LL - 1);
            #pragma unroll
            for (int sn = 0; sn < 4; sn++) {
                const int o = o0 + wn * 64 + sn * 16 + l16;
                const float val = (float)acc[sm][sn][r] * mr + bias[o];
                if (widx == 3) {
                    outF[(size_t)t * EE + o] = val;
                } else {  // f16 [B,H,L,D] (Q with pre, K)
                    const int h_ = o >> 6, d_ = o & 63;
                    outH[((size_t)(b_ * HH + h_) * LL + l_) * DD + d_] = (_Float16)(val * pre);
                }
            }
        }
    }
}

// ---------------- MFMA 32x32 flash attention, 32q/wave, register-P -------------------
// Block = 4 waves = 128 q. S^T = K.Q^T (A=K from LDS, B=Q regs). P transposed
// C->A layout in registers via permlane32_swap (q = lane&31 in both halves).
// ctx = P.V^T. Fixed-max exp2 softmax; rtz f16 pack (normalization cancels bias).
// Row-sum via ones-MFMA: accl = mfma(pa, 1) gives lsum in the exact C-row layout
// used by the epilogue -> no per-lane adds, no epilogue shuffles.
// 2-phase double-buffered K/V staging; one __syncthreads() per iter.
// XCD-swizzled 1-D grid: each XCD owns 8 heads -> K/V working set = 4MB = one L2.
__global__ __launch_bounds__(256, 4) void k_attn5(const _Float16* __restrict__ Q,
                                                  const _Float16* __restrict__ K,
                                                  const _Float16* __restrict__ Vt,
                                                  float* __restrict__ ctx) {
    __shared__ __align__(16) _Float16 Ksh[2][64][64];    // [buf][key][d]
    __shared__ __align__(16) _Float16 Vtsh[2][64][64];   // [buf][d][key]
    const int tid = threadIdx.x;
    const int wv = tid >> 6, lane = tid & 63;
    const int l32 = lane & 31, h2 = lane >> 5;
    // XCD swizzle: consecutive block ids round-robin across 8 XCDs; give each
    // XCD 8 whole heads (8 x 512KB K/V = 4MB = one XCD L2). Bijective on 1024.
    const int bid = blockIdx.x;
    const int xcd = bid & 7, j = bid >> 3;          // j in [0,128)
    const int bh = (xcd << 3) | (j >> 4);           // head-group per XCD
    const int qblk = j & 15;
    const int b_ = bh >> 4, h_ = bh & 15;
    const int q0 = qblk * 128 + wv * 32;
    const int srow = lane >> 3, schunk = lane & 7;

    const _Float16* Qb = Q + (size_t)bh * LL * DD;
    const _Float16* Kb = K + (size_t)bh * LL * DD;
    const _Float16* Vtb = Vt + (size_t)bh * DD * LL;

    // Q B-frags: B[n=q=l32][k=d=ds*16+8*h2+j]; Q pre-scaled by 0.125*log2e
    half8 qf[4];
    #pragma unroll
    for (int ds = 0; ds < 4; ds++)
        qf[ds] = *(const half8*)(Qb + (size_t)(q0 + l32) * DD + ds * 16 + h2 * 8);

    floatx16 acc[2], accl, zv;
    #pragma unroll
    for (int r = 0; r < 16; r++) { acc[0][r] = 0.f; acc[1][r] = 0.f; accl[r] = 0.f; zv[r] = 0.f; }
    half8 ones;
    #pragma unroll
    for (int r = 0; r < 8; r++) ones[r] = (_Float16)1.0f;

    // prologue: stage tile 0 into buf 0
    {
        #pragma unroll
        for (int u = 0; u < 2; u++) {
            const int g = wv * 2 + u;                    // row-group 0..7
            const int c = schunk ^ srow ^ (g & 7);       // logical chunk
            const int row = g * 8 + srow;
            gl_lds16(Kb + (size_t)row * DD + c * 8, &Ksh[0][g * 8][0]);
            gl_lds16(Vtb + (size_t)row * LL + c * 8, &Vtsh[0][g * 8][0]);
        }
    }
    __syncthreads();

    for (int kt = 0; kt < LL; kt += 64) {
        const int cur = (kt >> 6) & 1;

        // issue next-tile stage into buf cur^1 (latency hides under compute)
        if (kt + 64 < LL) {
            const int nkt = kt + 64;
            #pragma unroll
            for (int u = 0; u < 2; u++) {
                const int g = wv * 2 + u;
                const int c = schunk ^ srow ^ (g & 7);
                const int row = g * 8 + srow;
                gl_lds16(Kb + (size_t)(nkt + row) * DD + c * 8, &Ksh[cur ^ 1][g * 8][0]);
                gl_lds16(Vtb + (size_t)row * LL + nkt + c * 8, &Vtsh[cur ^ 1][g * 8][0]);
            }
        }

        // ---- S^T + exp2 + register transpose to A-layout P ----
        half8 pa[4];
        #pragma unroll
        for (int ks = 0; ks < 2; ks++) {
            const int rowK = ks * 32 + l32;
            const int mK = (l32 & 7) ^ ((ks * 4 + (l32 >> 3)) & 7);
            __builtin_amdgcn_s_setprio(1);
            floatx16 sc;
            {
                const half8 kf = *(const half8*)&Ksh[cur][rowK][((2 * 0 + h2) ^ mK) * 8];
                sc = __builtin_amdgcn_mfma_f32_32x32x16_f16(kf, qf[0], zv, 0, 0, 0);
            }
            #pragma unroll
            for (int ds = 1; ds < 4; ds++) {
                const half8 kf = *(const half8*)&Ksh[cur][rowK][((2 * ds + h2) ^ mK) * 8];
                sc = __builtin_amdgcn_mfma_f32_32x32x16_f16(kf, qf[ds], sc, 0, 0, 0);
            }
            __builtin_amdgcn_s_setprio(0);
            // lane holds keys ks*32 + 8*c4 + 4*h2 + j  for q = l32
            float p[16];
            #pragma unroll
            for (int r = 0; r < 16; r++) p[r] = __builtin_amdgcn_exp2f(sc[r]);
            uint32_t u_[4][2];
            #pragma unroll
            for (int c4 = 0; c4 < 4; c4++) {
                u_[c4][0] = pkrtz(p[4 * c4 + 0], p[4 * c4 + 1]);
                u_[c4][1] = pkrtz(p[4 * c4 + 2], p[4 * c4 + 3]);
            }
            // A-frag words for kb = ks*2+mm: keys kb*16 + h2*8 + {0..7}.
            // permlane32_swap(A,B): ret0 = {A.lo-half, B.lo-half},
            //                       ret1 = {A.hi-half, B.hi-half} (per lane-half)
            #pragma unroll
            for (int mm = 0; mm < 2; mm++) {
                uint2v s0 = __builtin_amdgcn_permlane32_swap(
                    u_[2 * mm][0], u_[2 * mm + 1][0], false, false);
                uint2v s1 = __builtin_amdgcn_permlane32_swap(
                    u_[2 * mm][1], u_[2 * mm + 1][1], false, false);
                uintx4 w;
                w[0] = s0[0]; w[1] = s1[0]; w[2] = s0[1]; w[3] = s1[1];
                union { uintx4 u; half8 h; } cv; cv.u = w;
                pa[ks * 2 + mm] = cv.h;
            }
        }

        // ---- ctx += P . V^T ; row-sums += P . 1 ----
        __builtin_amdgcn_s_setprio(1);
        #pragma unroll
        for (int kb = 0; kb < 4; kb++) {
            #pragma unroll
            for (int sd = 0; sd < 2; sd++) {
                const int rowV = sd * 32 + l32;
                const int mV = (l32 & 7) ^ ((sd * 4 + (l32 >> 3)) & 7);
                const half8 vf = *(const half8*)&Vtsh[cur][rowV][((2 * kb + h2) ^ mV) * 8];
                acc[sd] = __builtin_amdgcn_mfma_f32_32x32x16_f16(pa[kb], vf, acc[sd], 0, 0, 0);
            }
            accl = __builtin_amdgcn_mfma_f32_32x32x16_f16(pa[kb], ones, accl, 0, 0, 0);
        }
        __builtin_amdgcn_s_setprio(0);

        // drain own prefetch (vmcnt) + all waves done reading buf cur
        __syncthreads();
    }

    // ---- epilogue: ctx [B, L, E] fp32; accl[r] = lsum for this row ----
    #pragma unroll
    for (int r = 0; r < 16; r++) {
        const int qrow = (r & 3) + 8 * (r >> 2) + 4 * h2;
        const float iv = 1.f / accl[r];
        float* cp = ctx + ((size_t)b_ * LL + q0 + qrow) * EE + h_ * DD + l32;
        cp[0]  = acc[0][r] * iv;
        cp[32] = acc[1][r] * iv;
    }
}

// ---------------- launcher ----------------
extern "C" void kernel_launch(void* const* d_in, const int* in_sizes, int n_in,
                              void* d_out, int out_size, void* d_ws, size_t ws_size,
                              hipStream_t stream) {
    const float* query      = (const float*)d_in[0];
    const float* key        = (const float*)d_in[1];
    const float* value      = (const float*)d_in[2];
    const float* in_proj_w  = (const float*)d_in[3];
    const float* in_proj_b  = (const float*)d_in[4];
    const float* out_proj_w = (const float*)d_in[5];
    const float* out_proj_b = (const float*)d_in[6];
    float* out = (float*)d_out;

    char* ws = (char*)d_ws;
    double*   sums   = (double*)ws;                             // 32 B
    float*    scaleF = (float*)(ws + 32);                       // 16 B
    float*    gbuf   = (float*)(ws + 256);                      // 4*TT floats
    int8_t*   qw8    = (int8_t*)(ws + (size_t)1  * 1024 * 1024);  // 4 MB ternary i8
    int8_t*   qx8    = (int8_t*)(ws + (size_t)8  * 1024 * 1024);  // 4 slabs x 8 MB
    _Float16* Qh     = (_Float16*)(ws + (size_t)40 * 1024 * 1024); // 3 slabs x 16 MB
    _Float16* Kh     = Qh + (size_t)TT * EE;
    _Float16* Vth    = Kh + (size_t)TT * EE;                    // V^T [B,H,D,L]
    float*    ctx    = out;   // d_out doubles as fp32 ctx scratch (fully overwritten)

    const float QPRE = 0.18033688011112042f;  // (1/8) * log2(e)

    hipMemsetAsync(sums, 0, 32, stream);
    k_absum<<<dim3(64, 4), 256, 0, stream>>>(in_proj_w, out_proj_w, sums);
    k_quantw<<<(4 * EE * EE) / 256, 256, 0, stream>>>(in_proj_w, out_proj_w, sums, scaleF, qw8);
    k_gammaq3<<<dim3(TT / 4, 3), 256, 0, stream>>>(query, key, value, gbuf, qx8);

    // fused Q/K/V^T projections (widx = blockIdx.z)
    k_bitmm<<<dim3(TT / 128, EE / 128, 3), 256, 0, stream>>>(
        qx8, gbuf, qw8, scaleF, in_proj_b, out_proj_b, nullptr, Qh, 0, QPRE);

    k_attn5<<<dim3((LL / 128) * BB * HH), 256, 0, stream>>>(Qh, Kh, Vth, ctx);

    // requantize ctx (slab 3) + out-projection
    k_gammaq<<<TT / 4, 256, 0, stream>>>(ctx, gbuf + 3 * TT, qx8 + 3 * (size_t)TT * EE);
    k_bitmm<<<dim3(TT / 128, EE / 128, 1), 256, 0, stream>>>(
        qx8, gbuf, qw8, scaleF, in_proj_b, out_proj_b, out, Qh, 3, QPRE);
}

// Round 5
// 333.927 us; speedup vs baseline: 1.0610x; 1.0196x over previous
//
#include <hip/hip_runtime.h>
#include <cstdint>
#include <cstddef>

#define BB 4
#define LL 2048
#define EE 1024
#define HH 16
#define DD 64
#define TT (BB*LL)      // 8192 tokens
#define EPSF 1e-5f

typedef _Float16 half8 __attribute__((ext_vector_type(8)));
typedef _Float16 half4v __attribute__((ext_vector_type(4)));
typedef float floatx4 __attribute__((ext_vector_type(4)));
typedef float floatx16 __attribute__((ext_vector_type(16)));
typedef int intx4 __attribute__((ext_vector_type(4)));
typedef unsigned int uintx4 __attribute__((ext_vector_type(4)));
typedef unsigned int uint2v __attribute__((ext_vector_type(2)));

__device__ __forceinline__ void gl_lds16(const void* g, void* l) {
    __builtin_amdgcn_global_load_lds(
        (const __attribute__((address_space(1))) void*)g,
        (__attribute__((address_space(3))) void*)l, 16, 0, 0);
}

// pack two fp32 -> two f16 (rtz, single VALU op v_cvt_pkrtz_f16_f32)
__device__ __forceinline__ uint32_t pkrtz(float a, float b) {
    return __builtin_bit_cast(uint32_t, __builtin_amdgcn_cvt_pkrtz(a, b));
}

// ---------------- kernel 1: per-tensor abs-sum (fp64 for determinism) ----------------
__global__ void k_absum(const float* __restrict__ in_proj,
                        const float* __restrict__ out_proj,
                        double* __restrict__ sums) {
    const int which = blockIdx.y;  // 0=q,1=k,2=v,3=o
    const float4* src = (const float4*)((which < 3) ? (in_proj + (size_t)which * EE * EE)
                                                    : out_proj);
    double loc = 0.0;
    const int n4 = EE * EE / 4;
    for (int i = blockIdx.x * blockDim.x + threadIdx.x; i < n4; i += gridDim.x * blockDim.x) {
        const float4 v = src[i];
        loc += (double)fabsf(v.x); loc += (double)fabsf(v.y);
        loc += (double)fabsf(v.z); loc += (double)fabsf(v.w);
    }
    #pragma unroll
    for (int off = 32; off > 0; off >>= 1) loc += __shfl_down(loc, off, 64);
    __shared__ double red[4];
    const int lane = threadIdx.x & 63, wv = threadIdx.x >> 6;
    if (lane == 0) red[wv] = loc;
    __syncthreads();
    if (threadIdx.x == 0) {
        double tot = red[0] + red[1] + red[2] + red[3];
        atomicAdd(&sums[which], tot);
    }
}

// ---------------- kernel 2: ternarize weights -> int8 {-1,0,1} ----------------
__global__ void k_quantw(const float* __restrict__ in_proj,
                         const float* __restrict__ out_proj,
                         const double* __restrict__ sums,
                         float* __restrict__ scaleF,
                         int8_t* __restrict__ qw) {
    const int idx = blockIdx.x * blockDim.x + threadIdx.x;  // exactly 4M threads
    if (idx < 4) scaleF[idx] = fmaxf((float)(sums[idx] * (1.0 / (EE * EE))), EPSF);
    const int which = idx >> 20;  // /(EE*EE)
    const float s = fmaxf((float)(sums[which] * (1.0 / (EE * EE))), EPSF);
    const float w = (which < 3) ? in_proj[idx] : out_proj[idx - 3 * EE * EE];
    float q = rintf(w / s);            // round-half-even, matches jnp.round
    q = fminf(fmaxf(q, -1.f), 1.f);
    qw[idx] = (int8_t)q;
}

// ---------------- gamma + int8 activation quantization (device body) ----------------
__device__ __forceinline__ void gammaq_body(const float* __restrict__ x,
                                            float* __restrict__ g,
                                            int8_t* __restrict__ qx) {
    const int wv = threadIdx.x >> 6, lane = threadIdx.x & 63;
    const int tok = blockIdx.x * 4 + wv;
    const float* xp = x + (size_t)tok * EE;
    float4 v[4];
    #pragma unroll
    for (int i = 0; i < 4; i++) v[i] = *(const float4*)(xp + (lane + 64 * i) * 4);
    float m = 0.f;
    #pragma unroll
    for (int i = 0; i < 4; i++)
        m = fmaxf(m, fmaxf(fmaxf(fabsf(v[i].x), fabsf(v[i].y)),
                           fmaxf(fabsf(v[i].z), fabsf(v[i].w))));
    #pragma unroll
    for (int off = 1; off < 64; off <<= 1) m = fmaxf(m, __shfl_xor(m, off, 64));
    const float gg = fmaxf(m, EPSF);
    const float rg = 128.f / gg;     // matches reference x * (q/gamma)
    int8_t* qp = qx + (size_t)tok * EE;
    #pragma unroll
    for (int i = 0; i < 4; i++) {
        char4 c;
        c.x = (int8_t)(int)fminf(fmaxf(rintf(v[i].x * rg), -128.f), 127.f);
        c.y = (int8_t)(int)fminf(fmaxf(rintf(v[i].y * rg), -128.f), 127.f);
        c.z = (int8_t)(int)fminf(fmaxf(rintf(v[i].z * rg), -128.f), 127.f);
        c.w = (int8_t)(int)fminf(fmaxf(rintf(v[i].w * rg), -128.f), 127.f);
        *(char4*)(qp + (lane + 64 * i) * 4) = c;
    }
    if (lane == 0) g[tok] = gg;
}

// merged q/k/v quantization: blockIdx.y selects tensor
__global__ __launch_bounds__(256) void k_gammaq3(const float* __restrict__ q,
                                                 const float* __restrict__ k,
                                                 const float* __restrict__ v,
                                                 float* __restrict__ g,
                                                 int8_t* __restrict__ qx) {
    const int y = blockIdx.y;
    const float* src = (y == 0) ? q : (y == 1) ? k : v;
    gammaq_body(src, g + (size_t)y * TT, qx + (size_t)y * TT * EE);
}

__global__ __launch_bounds__(256) void k_gammaq(const float* __restrict__ x,
                                                float* __restrict__ g,
                                                int8_t* __restrict__ qx) {
    gammaq_body(x, g, qx);
}

// ---------------- BitLinear via i8 MFMA (exact i32 integer arithmetic) ---------------
// block 128(t) x 128(o), BK=128, 4 waves 2x2, wave tile 64x64 (4x4 of 16x16x64 i8).
// LDS rows of 128 i8 = 8 x 16B chunks; logical chunk c of row R stored at phys
// c ^ (R&7) ^ ((R>>3)&7)  (full 3-term swizzle -> conflict-free frag reads).
// 2-phase double-buffered K-loop (prefetch k0+128 while computing k0), one
// __syncthreads per iter. 1-D XCD-swizzled grid: each XCD owns 8 contiguous
// t-chunks x all (o-panel, slab) -> weights L2-resident, qx read once per XCD.
// widx = wbase + z selects weight/activation slab and epilogue:
//   widx 0: f16 [B,H,L,D] * qpre (Q)   widx 1: f16 [B,H,L,D] (K)
//   widx 2: f16 V^T [B,H,D,L] via LDS transpose   widx 3: fp32 [T,E] (out-proj)
__global__ __launch_bounds__(256) void k_bitmm(
    const int8_t* __restrict__ qx_all, const float* __restrict__ gam_all,
    const int8_t* __restrict__ qw_all, const float* __restrict__ scaleF,
    const float* __restrict__ in_proj_b, const float* __restrict__ out_proj_b,
    float* __restrict__ outF, _Float16* __restrict__ outH_all,
    int wbase, float qpre) {
    __shared__ __align__(16) int8_t smem[65536];   // As[2]:0..32K, Bs[2]:32K..64K
    _Float16 (*Vt)[136] = (_Float16(*)[136])smem;  // mode-2 reuse after final sync

    // ---- XCD-swizzled decode: bid&7 = XCD; per XCD: 8 t-chunks x 8 o x nz ----
    const int nz = (wbase == 0) ? 3 : 1;
    const int bid = blockIdx.x;
    const int xcd = bid & 7;
    const int idx = bid >> 3;            // [0, 64*nz)
    const int per = 8 * nz;
    const int xl = idx / per;            // [0,8)
    const int rem = idx - xl * per;
    const int y = rem & 7;
    const int z = rem >> 3;              // [0,nz)
    const int t0 = (xcd * 8 + xl) * 128;
    const int o0 = y * 128;
    const int widx = wbase + z;

    const int8_t* qx = qx_all + (size_t)widx * TT * EE;
    const int8_t* qw = qw_all + (size_t)widx * EE * EE;
    const float* gam = gam_all + (size_t)widx * TT;
    const float* bias = (widx < 3) ? (in_proj_b + widx * EE) : out_proj_b;
    _Float16* outH = outH_all + (size_t)widx * TT * EE;   // slabs Q,K,Vt
    const float pre = (widx == 0) ? qpre : 1.0f;
    const int tid = threadIdx.x;
    const int wv = tid >> 6, lane = tid & 63;
    const int quad = lane >> 4, l16 = lane & 15;
    const int wm = wv & 1, wn = wv >> 1;
    const int srow = lane >> 3, schunk = lane & 7;

    intx4 acc[4][4];
    #pragma unroll
    for (int i = 0; i < 4; i++)
        #pragma unroll
        for (int j = 0; j < 4; j++) acc[i][j] = (intx4){0, 0, 0, 0};

    // prologue: stage k0=0 into buf 0
    #pragma unroll
    for (int p = 0; p < 4; p++) {
        const int g = wv * 4 + p;                    // row-group 0..15
        const int c = schunk ^ srow ^ (g & 7);       // logical chunk
        const int row = g * 8 + srow;
        gl_lds16(qx + (size_t)(t0 + row) * EE + c * 16, smem + (size_t)(g * 8) * 128);
        gl_lds16(qw + (size_t)(o0 + row) * EE + c * 16, smem + 32768 + (size_t)(g * 8) * 128);
    }
    __syncthreads();

    for (int k0 = 0; k0 < EE; k0 += 128) {
        const int cur = (k0 >> 7) & 1;
        int8_t (*As)[128] = (int8_t(*)[128])(smem + cur * 16384);
        int8_t (*Bs)[128] = (int8_t(*)[128])(smem + 32768 + cur * 16384);

        // prefetch next K-tile into buf cur^1 (latency hides under MFMA)
        if (k0 + 128 < EE) {
            int8_t* Asn = smem + (cur ^ 1) * 16384;
            int8_t* Bsn = smem + 32768 + (cur ^ 1) * 16384;
            const int kn = k0 + 128;
            #pragma unroll
            for (int p = 0; p < 4; p++) {
                const int g = wv * 4 + p;
                const int c = schunk ^ srow ^ (g & 7);
                const int row = g * 8 + srow;
                gl_lds16(qx + (size_t)(t0 + row) * EE + kn + c * 16, Asn + (size_t)(g * 8) * 128);
                gl_lds16(qw + (size_t)(o0 + row) * EE + kn + c * 16, Bsn + (size_t)(g * 8) * 128);
            }
        }

        #pragma unroll
        for (int kk = 0; kk < 2; kk++) {
            intx4 af[4], bf[4];
            #pragma unroll
            for (int s4 = 0; s4 < 4; s4++) {
                const int mR = (l16 & 7) ^ ((s4 * 2 + (l16 >> 3)) & 7);
                const int ph = ((kk * 4 + quad) ^ mR) * 16;
                af[s4] = *(const intx4*)&As[wm * 64 + s4 * 16 + l16][ph];
                bf[s4] = *(const intx4*)&Bs[wn * 64 + s4 * 16 + l16][ph];
            }
            __builtin_amdgcn_s_setprio(1);
            #pragma unroll
            for (int sm = 0; sm < 4; sm++)
                #pragma unroll
                for (int sn = 0; sn < 4; sn++)
                    acc[sm][sn] = __builtin_amdgcn_mfma_i32_16x16x64_i8(
                        af[sm], bf[sn], acc[sm][sn], 0, 0, 0);
            __builtin_amdgcn_s_setprio(0);
        }
        // drain own prefetch (vmcnt) + all waves done reading buf cur
        __syncthreads();
    }

    const float s = scaleF[widx];
    if (widx == 2) {
        // V^T: stage f16 into LDS [o][t] then coalesced store along t (=L)
        #pragma unroll
        for (int sm = 0; sm < 4; sm++) {
            const int tl = wm * 64 + sm * 16 + quad * 4;
            float mr[4];
            #pragma unroll
            for (int r = 0; r < 4; r++) mr[r] = s * gam[t0 + tl + r] * 0.0078125f;
            #pragma unroll
            for (int sn = 0; sn < 4; sn++) {
                const int ol = wn * 64 + sn * 16 + l16;
                const float b = bias[o0 + ol];
                half4v hv;
                #pragma unroll
                for (int r = 0; r < 4; r++)
                    hv[r] = (_Float16)((float)acc[sm][sn][r] * mr[r] + b);
                *(half4v*)&Vt[ol][tl] = hv;
            }
        }
        __syncthreads();
        const int ol2 = tid >> 1, tc0 = (tid & 1) * 64;
        const int og = o0 + ol2, hh = og >> 6, dd = og & 63;
        const int bb = t0 >> 11, l0 = t0 & (LL - 1);
        _Float16* dst = outH + ((size_t)(bb * HH + hh) * DD + dd) * LL + l0 + tc0;
        #pragma unroll
        for (int i = 0; i < 8; i++)
            *(half8*)(dst + i * 8) = *(const half8*)&Vt[ol2][tc0 + i * 8];
        return;
    }
    #pragma unroll
    for (int sm = 0; sm < 4; sm++) {
        #pragma unroll
        for (int r = 0; r < 4; r++) {
            const int t = t0 + wm * 64 + sm * 16 + quad * 4 + r;
            const float mr = s * gam[t] * 0.0078125f;   // s*g/128
            const int b_ = t >> 11, l_ = t & (LL - 1);
            #pragma unroll
            for (int sn = 0; sn < 4; sn++) {
                const int o = o0 + wn * 64 + sn * 16 + l16;
                const float val = (float)acc[sm][sn][r] * mr + bias[o];
                if (widx == 3) {
                    outF[(size_t)t * EE + o] = val;
                } else {  // f16 [B,H,L,D] (Q with pre, K)
                    const int h_ = o >> 6, d_ = o & 63;
                    outH[((size_t)(b_ * HH + h_) * LL + l_) * DD + d_] = (_Float16)(val * pre);
                }
            }
        }
    }
}

// ---------------- MFMA 32x32 flash attention, 32q/wave, register-P -------------------
// Block = 4 waves = 128 q. S^T = K.Q^T (A=K from LDS, B=Q regs). P transposed
// C->A layout in registers via permlane32_swap (q = lane&31 in both halves).
// ctx = P.V^T. Fixed-max exp2 softmax; rtz f16 pack (normalization cancels bias).
// Row-sum via ones-MFMA: accl = mfma(pa, 1) gives lsum in the exact C-row layout
// used by the epilogue -> no per-lane adds, no epilogue shuffles.
// 2-phase double-buffered K/V staging; one __syncthreads() per iter.
// XCD-swizzled 1-D grid: each XCD owns 8 heads -> K/V working set = 4MB = one L2.
__global__ __launch_bounds__(256, 4) void k_attn5(const _Float16* __restrict__ Q,
                                                  const _Float16* __restrict__ K,
                                                  const _Float16* __restrict__ Vt,
                                                  float* __restrict__ ctx) {
    __shared__ __align__(16) _Float16 Ksh[2][64][64];    // [buf][key][d]
    __shared__ __align__(16) _Float16 Vtsh[2][64][64];   // [buf][d][key]
    const int tid = threadIdx.x;
    const int wv = tid >> 6, lane = tid & 63;
    const int l32 = lane & 31, h2 = lane >> 5;
    // XCD swizzle: consecutive block ids round-robin across 8 XCDs; give each
    // XCD 8 whole heads (8 x 512KB K/V = 4MB = one XCD L2). Bijective on 1024.
    const int bid = blockIdx.x;
    const int xcd = bid & 7, j = bid >> 3;          // j in [0,128)
    const int bh = (xcd << 3) | (j >> 4);           // head-group per XCD
    const int qblk = j & 15;
    const int b_ = bh >> 4, h_ = bh & 15;
    const int q0 = qblk * 128 + wv * 32;
    const int srow = lane >> 3, schunk = lane & 7;

    const _Float16* Qb = Q + (size_t)bh * LL * DD;
    const _Float16* Kb = K + (size_t)bh * LL * DD;
    const _Float16* Vtb = Vt + (size_t)bh * DD * LL;

    // Q B-frags: B[n=q=l32][k=d=ds*16+8*h2+j]; Q pre-scaled by 0.125*log2e
    half8 qf[4];
    #pragma unroll
    for (int ds = 0; ds < 4; ds++)
        qf[ds] = *(const half8*)(Qb + (size_t)(q0 + l32) * DD + ds * 16 + h2 * 8);

    floatx16 acc[2], accl, zv;
    #pragma unroll
    for (int r = 0; r < 16; r++) { acc[0][r] = 0.f; acc[1][r] = 0.f; accl[r] = 0.f; zv[r] = 0.f; }
    half8 ones;
    #pragma unroll
    for (int r = 0; r < 8; r++) ones[r] = (_Float16)1.0f;

    // prologue: stage tile 0 into buf 0
    {
        #pragma unroll
        for (int u = 0; u < 2; u++) {
            const int g = wv * 2 + u;                    // row-group 0..7
            const int c = schunk ^ srow ^ (g & 7);       // logical chunk
            const int row = g * 8 + srow;
            gl_lds16(Kb + (size_t)row * DD + c * 8, &Ksh[0][g * 8][0]);
            gl_lds16(Vtb + (size_t)row * LL + c * 8, &Vtsh[0][g * 8][0]);
        }
    }
    __syncthreads();

    for (int kt = 0; kt < LL; kt += 64) {
        const int cur = (kt >> 6) & 1;

        // issue next-tile stage into buf cur^1 (latency hides under compute)
        if (kt + 64 < LL) {
            const int nkt = kt + 64;
            #pragma unroll
            for (int u = 0; u < 2; u++) {
                const int g = wv * 2 + u;
                const int c = schunk ^ srow ^ (g & 7);
                const int row = g * 8 + srow;
                gl_lds16(Kb + (size_t)(nkt + row) * DD + c * 8, &Ksh[cur ^ 1][g * 8][0]);
                gl_lds16(Vtb + (size_t)row * LL + nkt + c * 8, &Vtsh[cur ^ 1][g * 8][0]);
            }
        }

        // ---- S^T + exp2 + register transpose to A-layout P ----
        half8 pa[4];
        #pragma unroll
        for (int ks = 0; ks < 2; ks++) {
            const int rowK = ks * 32 + l32;
            const int mK = (l32 & 7) ^ ((ks * 4 + (l32 >> 3)) & 7);
            __builtin_amdgcn_s_setprio(1);
            floatx16 sc;
            {
                const half8 kf = *(const half8*)&Ksh[cur][rowK][((2 * 0 + h2) ^ mK) * 8];
                sc = __builtin_amdgcn_mfma_f32_32x32x16_f16(kf, qf[0], zv, 0, 0, 0);
            }
            #pragma unroll
            for (int ds = 1; ds < 4; ds++) {
                const half8 kf = *(const half8*)&Ksh[cur][rowK][((2 * ds + h2) ^ mK) * 8];
                sc = __builtin_amdgcn_mfma_f32_32x32x16_f16(kf, qf[ds], sc, 0, 0, 0);
            }
            __builtin_amdgcn_s_setprio(0);
            // lane holds keys ks*32 + 8*c4 + 4*h2 + j  for q = l32
            float p[16];
            #pragma unroll
            for (int r = 0; r < 16; r++) p[r] = __builtin_amdgcn_exp2f(sc[r]);
            uint32_t u_[4][2];
            #pragma unroll
            for (int c4 = 0; c4 < 4; c4++) {
                u_[c4][0] = pkrtz(p[4 * c4 + 0], p[4 * c4 + 1]);
                u_[c4][1] = pkrtz(p[4 * c4 + 2], p[4 * c4 + 3]);
            }
            // A-frag words for kb = ks*2+mm: keys kb*16 + h2*8 + {0..7}.
            // permlane32_swap(A,B): ret0 = {A.lo-half, B.lo-half},
            //                       ret1 = {A.hi-half, B.hi-half} (per lane-half)
            #pragma unroll
            for (int mm = 0; mm < 2; mm++) {
                uint2v s0 = __builtin_amdgcn_permlane32_swap(
                    u_[2 * mm][0], u_[2 * mm + 1][0], false, false);
                uint2v s1 = __builtin_amdgcn_permlane32_swap(
                    u_[2 * mm][1], u_[2 * mm + 1][1], false, false);
                uintx4 w;
                w[0] = s0[0]; w[1] = s1[0]; w[2] = s0[1]; w[3] = s1[1];
                union { uintx4 u; half8 h; } cv; cv.u = w;
                pa[ks * 2 + mm] = cv.h;
            }
        }

        // ---- ctx += P . V^T ; row-sums += P . 1 ----
        __builtin_amdgcn_s_setprio(1);
        #pragma unroll
        for (int kb = 0; kb < 4; kb++) {
            #pragma unroll
            for (int sd = 0; sd < 2; sd++) {
                const int rowV = sd * 32 + l32;
                const int mV = (l32 & 7) ^ ((sd * 4 + (l32 >> 3)) & 7);
                const half8 vf = *(const half8*)&Vtsh[cur][rowV][((2 * kb + h2) ^ mV) * 8];
                acc[sd] = __builtin_amdgcn_mfma_f32_32x32x16_f16(pa[kb], vf, acc[sd], 0, 0, 0);
            }
            accl = __builtin_amdgcn_mfma_f32_32x32x16_f16(pa[kb], ones, accl, 0, 0, 0);
        }
        __builtin_amdgcn_s_setprio(0);

        // drain own prefetch (vmcnt) + all waves done reading buf cur
        __syncthreads();
    }

    // ---- epilogue: ctx [B, L, E] fp32; accl[r] = lsum for this row ----
    #pragma unroll
    for (int r = 0; r < 16; r++) {
        const int qrow = (r & 3) + 8 * (r >> 2) + 4 * h2;
        const float iv = 1.f / accl[r];
        float* cp = ctx + ((size_t)b_ * LL + q0 + qrow) * EE + h_ * DD + l32;
        cp[0]  = acc[0][r] * iv;
        cp[32] = acc[1][r] * iv;
    }
}

// ---------------- launcher ----------------
extern "C" void kernel_launch(void* const* d_in, const int* in_sizes, int n_in,
                              void* d_out, int out_size, void* d_ws, size_t ws_size,
                              hipStream_t stream) {
    const float* query      = (const float*)d_in[0];
    const float* key        = (const float*)d_in[1];
    const float* value      = (const float*)d_in[2];
    const float* in_proj_w  = (const float*)d_in[3];
    const float* in_proj_b  = (const float*)d_in[4];
    const float* out_proj_w = (const float*)d_in[5];
    const float* out_proj_b = (const float*)d_in[6];
    float* out = (float*)d_out;

    char* ws = (char*)d_ws;
    double*   sums   = (double*)ws;                             // 32 B
    float*    scaleF = (float*)(ws + 32);                       // 16 B
    float*    gbuf   = (float*)(ws + 256);                      // 4*TT floats
    int8_t*   qw8    = (int8_t*)(ws + (size_t)1  * 1024 * 1024);  // 4 MB ternary i8
    int8_t*   qx8    = (int8_t*)(ws + (size_t)8  * 1024 * 1024);  // 4 slabs x 8 MB
    _Float16* Qh     = (_Float16*)(ws + (size_t)40 * 1024 * 1024); // 3 slabs x 16 MB
    _Float16* Kh     = Qh + (size_t)TT * EE;
    _Float16* Vth    = Kh + (size_t)TT * EE;                    // V^T [B,H,D,L]
    float*    ctx    = out;   // d_out doubles as fp32 ctx scratch (fully overwritten)

    const float QPRE = 0.18033688011112042f;  // (1/8) * log2(e)

    hipMemsetAsync(sums, 0, 32, stream);
    k_absum<<<dim3(256, 4), 256, 0, stream>>>(in_proj_w, out_proj_w, sums);
    k_quantw<<<(4 * EE * EE) / 256, 256, 0, stream>>>(in_proj_w, out_proj_w, sums, scaleF, qw8);
    k_gammaq3<<<dim3(TT / 4, 3), 256, 0, stream>>>(query, key, value, gbuf, qx8);

    // fused Q/K/V^T projections (1-D XCD-swizzled grid, 64x8x3 blocks)
    k_bitmm<<<dim3(64 * 8 * 3), 256, 0, stream>>>(
        qx8, gbuf, qw8, scaleF, in_proj_b, out_proj_b, nullptr, Qh, 0, QPRE);

    k_attn5<<<dim3((LL / 128) * BB * HH), 256, 0, stream>>>(Qh, Kh, Vth, ctx);

    // requantize ctx (slab 3) + out-projection (1-D XCD-swizzled grid, 64x8 blocks)
    k_gammaq<<<TT / 4, 256, 0, stream>>>(ctx, gbuf + 3 * TT, qx8 + 3 * (size_t)TT * EE);
    k_bitmm<<<dim3(64 * 8), 256, 0, stream>>>(
        qx8, gbuf, qw8, scaleF, in_proj_b, out_proj_b, out, Qh, 3, QPRE);
}

// Round 6
// 332.863 us; speedup vs baseline: 1.0644x; 1.0032x over previous
//
#include <hip/hip_runtime.h>
#include <cstdint>
#include <cstddef>

#define BB 4
#define LL 2048
#define EE 1024
#define HH 16
#define DD 64
#define TT (BB*LL)      // 8192 tokens
#define EPSF 1e-5f

typedef _Float16 half8 __attribute__((ext_vector_type(8)));
typedef _Float16 half4v __attribute__((ext_vector_type(4)));
typedef float floatx4 __attribute__((ext_vector_type(4)));
typedef float floatx16 __attribute__((ext_vector_type(16)));
typedef int intx4 __attribute__((ext_vector_type(4)));
typedef unsigned int uintx4 __attribute__((ext_vector_type(4)));
typedef unsigned int uint2v __attribute__((ext_vector_type(2)));

__device__ __forceinline__ void gl_lds16(const void* g, void* l) {
    __builtin_amdgcn_global_load_lds(
        (const __attribute__((address_space(1))) void*)g,
        (__attribute__((address_space(3))) void*)l, 16, 0, 0);
}

// pack two fp32 -> two f16 (rtz, single VALU op v_cvt_pkrtz_f16_f32)
__device__ __forceinline__ uint32_t pkrtz(float a, float b) {
    return __builtin_bit_cast(uint32_t, __builtin_amdgcn_cvt_pkrtz(a, b));
}

// ---------------- kernel 1: per-tensor abs-sum (fp64 for determinism) ----------------
__global__ void k_absum(const float* __restrict__ in_proj,
                        const float* __restrict__ out_proj,
                        double* __restrict__ sums) {
    const int which = blockIdx.y;  // 0=q,1=k,2=v,3=o
    const float4* src = (const float4*)((which < 3) ? (in_proj + (size_t)which * EE * EE)
                                                    : out_proj);
    double loc = 0.0;
    const int n4 = EE * EE / 4;
    for (int i = blockIdx.x * blockDim.x + threadIdx.x; i < n4; i += gridDim.x * blockDim.x) {
        const float4 v = src[i];
        loc += (double)fabsf(v.x); loc += (double)fabsf(v.y);
        loc += (double)fabsf(v.z); loc += (double)fabsf(v.w);
    }
    #pragma unroll
    for (int off = 32; off > 0; off >>= 1) loc += __shfl_down(loc, off, 64);
    __shared__ double red[4];
    const int lane = threadIdx.x & 63, wv = threadIdx.x >> 6;
    if (lane == 0) red[wv] = loc;
    __syncthreads();
    if (threadIdx.x == 0) {
        double tot = red[0] + red[1] + red[2] + red[3];
        atomicAdd(&sums[which], tot);
    }
}

// ---------------- kernel 2: ternarize weights -> int8 {-1,0,1} ----------------
__global__ void k_quantw(const float* __restrict__ in_proj,
                         const float* __restrict__ out_proj,
                         const double* __restrict__ sums,
                         float* __restrict__ scaleF,
                         int8_t* __restrict__ qw) {
    const int idx = blockIdx.x * blockDim.x + threadIdx.x;  // exactly 4M threads
    if (idx < 4) scaleF[idx] = fmaxf((float)(sums[idx] * (1.0 / (EE * EE))), EPSF);
    const int which = idx >> 20;  // /(EE*EE)
    const float s = fmaxf((float)(sums[which] * (1.0 / (EE * EE))), EPSF);
    const float w = (which < 3) ? in_proj[idx] : out_proj[idx - 3 * EE * EE];
    float q = rintf(w / s);            // round-half-even, matches jnp.round
    q = fminf(fmaxf(q, -1.f), 1.f);
    qw[idx] = (int8_t)q;
}

// ---------------- gamma + int8 activation quantization (device body) ----------------
__device__ __forceinline__ void gammaq_body(const float* __restrict__ x,
                                            float* __restrict__ g,
                                            int8_t* __restrict__ qx) {
    const int wv = threadIdx.x >> 6, lane = threadIdx.x & 63;
    const int tok = blockIdx.x * 4 + wv;
    const float* xp = x + (size_t)tok * EE;
    float4 v[4];
    #pragma unroll
    for (int i = 0; i < 4; i++) v[i] = *(const float4*)(xp + (lane + 64 * i) * 4);
    float m = 0.f;
    #pragma unroll
    for (int i = 0; i < 4; i++)
        m = fmaxf(m, fmaxf(fmaxf(fabsf(v[i].x), fabsf(v[i].y)),
                           fmaxf(fabsf(v[i].z), fabsf(v[i].w))));
    #pragma unroll
    for (int off = 1; off < 64; off <<= 1) m = fmaxf(m, __shfl_xor(m, off, 64));
    const float gg = fmaxf(m, EPSF);
    const float rg = 128.f / gg;     // matches reference x * (q/gamma)
    int8_t* qp = qx + (size_t)tok * EE;
    #pragma unroll
    for (int i = 0; i < 4; i++) {
        char4 c;
        c.x = (int8_t)(int)fminf(fmaxf(rintf(v[i].x * rg), -128.f), 127.f);
        c.y = (int8_t)(int)fminf(fmaxf(rintf(v[i].y * rg), -128.f), 127.f);
        c.z = (int8_t)(int)fminf(fmaxf(rintf(v[i].z * rg), -128.f), 127.f);
        c.w = (int8_t)(int)fminf(fmaxf(rintf(v[i].w * rg), -128.f), 127.f);
        *(char4*)(qp + (lane + 64 * i) * 4) = c;
    }
    if (lane == 0) g[tok] = gg;
}

// merged q/k/v quantization: blockIdx.y selects tensor
__global__ __launch_bounds__(256) void k_gammaq3(const float* __restrict__ q,
                                                 const float* __restrict__ k,
                                                 const float* __restrict__ v,
                                                 float* __restrict__ g,
                                                 int8_t* __restrict__ qx) {
    const int y = blockIdx.y;
    const float* src = (y == 0) ? q : (y == 1) ? k : v;
    gammaq_body(src, g + (size_t)y * TT, qx + (size_t)y * TT * EE);
}

__global__ __launch_bounds__(256) void k_gammaq(const float* __restrict__ x,
                                                float* __restrict__ g,
                                                int8_t* __restrict__ qx) {
    gammaq_body(x, g, qx);
}

// ---------------- BitLinear via i8 MFMA (exact i32 integer arithmetic) ---------------
// block 128(t) x 128(o), BK=128, 4 waves 2x2, wave tile 64x64 (4x4 of 16x16x64 i8).
// LDS rows of 128 i8 = 8 x 16B chunks; logical chunk c of row R stored at phys
// c ^ (R&7) ^ ((R>>3)&7)  (full 3-term swizzle -> conflict-free frag reads).
// 2-phase double-buffered K-loop (prefetch k0+128 while computing k0), one
// __syncthreads per iter. 1-D XCD-swizzled grid: each XCD owns 8 contiguous
// t-chunks x all (o-panel, slab) -> weights L2-resident, qx read once per XCD.
// widx = wbase + z selects weight/activation slab and epilogue:
//   widx 0: f16 [B,H,L,D] * qpre (Q)   widx 1: f16 [B,H,L,D] (K)
//   widx 2: f16 V^T [B,H,D,L] via LDS transpose   widx 3: fp32 [T,E] (out-proj)
__global__ __launch_bounds__(256) void k_bitmm(
    const int8_t* __restrict__ qx_all, const float* __restrict__ gam_all,
    const int8_t* __restrict__ qw_all, const float* __restrict__ scaleF,
    const float* __restrict__ in_proj_b, const float* __restrict__ out_proj_b,
    float* __restrict__ outF, _Float16* __restrict__ outH_all,
    int wbase, float qpre) {
    __shared__ __align__(16) int8_t smem[65536];   // As[2]:0..32K, Bs[2]:32K..64K
    _Float16 (*Vt)[136] = (_Float16(*)[136])smem;  // mode-2 reuse after final sync

    // ---- XCD-swizzled decode: bid&7 = XCD; per XCD: 8 t-chunks x 8 o x nz ----
    const int nz = (wbase == 0) ? 3 : 1;
    const int bid = blockIdx.x;
    const int xcd = bid & 7;
    const int idx = bid >> 3;            // [0, 64*nz)
    const int per = 8 * nz;
    const int xl = idx / per;            // [0,8)
    const int rem = idx - xl * per;
    const int y = rem & 7;
    const int z = rem >> 3;              // [0,nz)
    const int t0 = (xcd * 8 + xl) * 128;
    const int o0 = y * 128;
    const int widx = wbase + z;

    const int8_t* qx = qx_all + (size_t)widx * TT * EE;
    const int8_t* qw = qw_all + (size_t)widx * EE * EE;
    const float* gam = gam_all + (size_t)widx * TT;
    const float* bias = (widx < 3) ? (in_proj_b + widx * EE) : out_proj_b;
    _Float16* outH = outH_all + (size_t)widx * TT * EE;   // slabs Q,K,Vt
    const float pre = (widx == 0) ? qpre : 1.0f;
    const int tid = threadIdx.x;
    const int wv = tid >> 6, lane = tid & 63;
    const int quad = lane >> 4, l16 = lane & 15;
    const int wm = wv & 1, wn = wv >> 1;
    const int srow = lane >> 3, schunk = lane & 7;

    intx4 acc[4][4];
    #pragma unroll
    for (int i = 0; i < 4; i++)
        #pragma unroll
        for (int j = 0; j < 4; j++) acc[i][j] = (intx4){0, 0, 0, 0};

    // prologue: stage k0=0 into buf 0
    #pragma unroll
    for (int p = 0; p < 4; p++) {
        const int g = wv * 4 + p;                    // row-group 0..15
        const int c = schunk ^ srow ^ (g & 7);       // logical chunk
        const int row = g * 8 + srow;
        gl_lds16(qx + (size_t)(t0 + row) * EE + c * 16, smem + (size_t)(g * 8) * 128);
        gl_lds16(qw + (size_t)(o0 + row) * EE + c * 16, smem + 32768 + (size_t)(g * 8) * 128);
    }
    __syncthreads();

    for (int k0 = 0; k0 < EE; k0 += 128) {
        const int cur = (k0 >> 7) & 1;
        int8_t (*As)[128] = (int8_t(*)[128])(smem + cur * 16384);
        int8_t (*Bs)[128] = (int8_t(*)[128])(smem + 32768 + cur * 16384);

        // prefetch next K-tile into buf cur^1 (latency hides under MFMA)
        if (k0 + 128 < EE) {
            int8_t* Asn = smem + (cur ^ 1) * 16384;
            int8_t* Bsn = smem + 32768 + (cur ^ 1) * 16384;
            const int kn = k0 + 128;
            #pragma unroll
            for (int p = 0; p < 4; p++) {
                const int g = wv * 4 + p;
                const int c = schunk ^ srow ^ (g & 7);
                const int row = g * 8 + srow;
                gl_lds16(qx + (size_t)(t0 + row) * EE + kn + c * 16, Asn + (size_t)(g * 8) * 128);
                gl_lds16(qw + (size_t)(o0 + row) * EE + kn + c * 16, Bsn + (size_t)(g * 8) * 128);
            }
        }

        #pragma unroll
        for (int kk = 0; kk < 2; kk++) {
            intx4 af[4], bf[4];
            #pragma unroll
            for (int s4 = 0; s4 < 4; s4++) {
                const int mR = (l16 & 7) ^ ((s4 * 2 + (l16 >> 3)) & 7);
                const int ph = ((kk * 4 + quad) ^ mR) * 16;
                af[s4] = *(const intx4*)&As[wm * 64 + s4 * 16 + l16][ph];
                bf[s4] = *(const intx4*)&Bs[wn * 64 + s4 * 16 + l16][ph];
            }
            __builtin_amdgcn_s_setprio(1);
            #pragma unroll
            for (int sm = 0; sm < 4; sm++)
                #pragma unroll
                for (int sn = 0; sn < 4; sn++)
                    acc[sm][sn] = __builtin_amdgcn_mfma_i32_16x16x64_i8(
                        af[sm], bf[sn], acc[sm][sn], 0, 0, 0);
            __builtin_amdgcn_s_setprio(0);
        }
        // drain own prefetch (vmcnt) + all waves done reading buf cur
        __syncthreads();
    }

    const float s = scaleF[widx];
    if (widx == 2) {
        // V^T: stage f16 into LDS [o][t] then coalesced store along t (=L)
        #pragma unroll
        for (int sm = 0; sm < 4; sm++) {
            const int tl = wm * 64 + sm * 16 + quad * 4;
            float mr[4];
            #pragma unroll
            for (int r = 0; r < 4; r++) mr[r] = s * gam[t0 + tl + r] * 0.0078125f;
            #pragma unroll
            for (int sn = 0; sn < 4; sn++) {
                const int ol = wn * 64 + sn * 16 + l16;
                const float b = bias[o0 + ol];
                half4v hv;
                #pragma unroll
                for (int r = 0; r < 4; r++)
                    hv[r] = (_Float16)((float)acc[sm][sn][r] * mr[r] + b);
                *(half4v*)&Vt[ol][tl] = hv;
            }
        }
        __syncthreads();
        const int ol2 = tid >> 1, tc0 = (tid & 1) * 64;
        const int og = o0 + ol2, hh = og >> 6, dd = og & 63;
        const int bb = t0 >> 11, l0 = t0 & (LL - 1);
        _Float16* dst = outH + ((size_t)(bb * HH + hh) * DD + dd) * LL + l0 + tc0;
        #pragma unroll
        for (int i = 0; i < 8; i++)
            *(half8*)(dst + i * 8) = *(const half8*)&Vt[ol2][tc0 + i * 8];
        return;
    }
    #pragma unroll
    for (int sm = 0; sm < 4; sm++) {
        #pragma unroll
        for (int r = 0; r < 4; r++) {
            const int t = t0 + wm * 64 + sm * 16 + quad * 4 + r;
            const float mr = s * gam[t] * 0.0078125f;   // s*g/128
            const int b_ = t >> 11, l_ = t & (LL - 1);
            #pragma unroll
            for (int sn = 0; sn < 4; sn++) {
                const int o = o0 + wn * 64 + sn * 16 + l16;
                const float val = (float)acc[sm][sn][r] * mr + bias[o];
                if (widx == 3) {
                    outF[(size_t)t * EE + o] = val;
                } else {  // f16 [B,H,L,D] (Q with pre, K)
                    const int h_ = o >> 6, d_ = o & 63;
                    outH[((size_t)(b_ * HH + h_) * LL + l_) * DD + d_] = (_Float16)(val * pre);
                }
            }
        }
    }
}

// ---------------- MFMA 32x32 flash attention, PV-deferred software pipeline ----------
// Block = 4 waves = 128 q. S^T = K.Q^T (A=K from LDS, B=Q regs). P transposed
// C->A layout in registers via permlane32_swap. ctx = P.V^T, row-sum via ones-MFMA.
// Per iter: stage(t+1) -> QK(t) [8 MFMA] -> PV(t-1) [12 MFMA, paP from prev iter]
// -> softmax(t)->paP -> one __syncthreads. The 20-MFMA cluster has no VALU dep;
// softmax overlaps other waves' MFMA clusters. K double-buffered, V TRIPLE-buffered
// (PV reads V(t-1) while V(t+1) stages). LDS 40KB. Swizzle offsets hoisted (offX).
// XCD-swizzled 1-D grid: each XCD owns 8 heads -> K/V working set = 4MB = one L2.
__global__ __launch_bounds__(256, 3) void k_attn5(const _Float16* __restrict__ Q,
                                                  const _Float16* __restrict__ K,
                                                  const _Float16* __restrict__ Vt,
                                                  float* __restrict__ ctx) {
    __shared__ __align__(16) _Float16 sm[5 * 64 * 64];  // K: 0,4096; V: 8192+vi*4096
    const int tid = threadIdx.x;
    const int wv = tid >> 6, lane = tid & 63;
    const int l32 = lane & 31, h2 = lane >> 5;
    const int bid = blockIdx.x;
    const int xcd = bid & 7, j = bid >> 3;          // j in [0,128)
    const int bh = (xcd << 3) | (j >> 4);           // head-group per XCD
    const int qblk = j & 15;
    const int b_ = bh >> 4, h_ = bh & 15;
    const int q0 = qblk * 128 + wv * 32;
    const int srow = lane >> 3, schunk = lane & 7;

    const _Float16* Qb = Q + (size_t)bh * LL * DD;
    const _Float16* Kb = K + (size_t)bh * LL * DD;
    const _Float16* Vtb = Vt + (size_t)bh * DD * LL;

    // Q B-frags: B[n=q=l32][k=d=ds*16+8*h2+j]; Q pre-scaled by 0.125*log2e
    half8 qf[4];
    #pragma unroll
    for (int ds = 0; ds < 4; ds++)
        qf[ds] = *(const half8*)(Qb + (size_t)(q0 + l32) * DD + ds * 16 + h2 * 8);

    // loop-invariant swizzled fragment-read offsets (elements):
    // row h*32+l32, chunk j: ((2j+h2)^mx)*8 with mx=(l32&7)^((h*4+(l32>>3))&7)
    int offX[2][4];
    #pragma unroll
    for (int h = 0; h < 2; h++) {
        const int mx = (l32 & 7) ^ ((h * 4 + (l32 >> 3)) & 7);
        #pragma unroll
        for (int jj = 0; jj < 4; jj++)
            offX[h][jj] = (h * 32 + l32) * 64 + (((2 * jj + h2) ^ mx) * 8);
    }

    floatx16 acc[2], accl, zv;
    #pragma unroll
    for (int r = 0; r < 16; r++) { acc[0][r] = 0.f; acc[1][r] = 0.f; accl[r] = 0.f; zv[r] = 0.f; }
    half8 ones;
    #pragma unroll
    for (int r = 0; r < 8; r++) ones[r] = (_Float16)1.0f;
    half8 paP[4];

#define STAGE_T(kt_, koff_, voff_)                                                   \
    {                                                                                \
        _Pragma("unroll")                                                            \
        for (int u = 0; u < 2; u++) {                                                \
            const int g = wv * 2 + u;                                                \
            const int c = schunk ^ srow ^ (g & 7);                                   \
            const int row = g * 8 + srow;                                            \
            gl_lds16(Kb + (size_t)((kt_) + row) * DD + c * 8, sm + (koff_) + g * 8 * 64); \
            gl_lds16(Vtb + (size_t)row * LL + (kt_) + c * 8, sm + (voff_) + g * 8 * 64);  \
        }                                                                            \
    }

#define QK_T(koff_)                                                                  \
    {                                                                                \
        const _Float16* kb_ = sm + (koff_);                                          \
        sc0 = __builtin_amdgcn_mfma_f32_32x32x16_f16(                                \
            *(const half8*)(kb_ + offX[0][0]), qf[0], zv, 0, 0, 0);                  \
        sc1 = __builtin_amdgcn_mfma_f32_32x32x16_f16(                                \
            *(const half8*)(kb_ + offX[1][0]), qf[0], zv, 0, 0, 0);                  \
        _Pragma("unroll")                                                            \
        for (int ds = 1; ds < 4; ds++) {                                             \
            sc0 = __builtin_amdgcn_mfma_f32_32x32x16_f16(                            \
                *(const half8*)(kb_ + offX[0][ds]), qf[ds], sc0, 0, 0, 0);           \
            sc1 = __builtin_amdgcn_mfma_f32_32x32x16_f16(                            \
                *(const half8*)(kb_ + offX[1][ds]), qf[ds], sc1, 0, 0, 0);           \
        }                                                                            \
    }

#define PV_T(voff_)                                                                  \
    {                                                                                \
        const _Float16* vb_ = sm + (voff_);                                          \
        _Pragma("unroll")                                                            \
        for (int kb = 0; kb < 4; kb++) {                                             \
            acc[0] = __builtin_amdgcn_mfma_f32_32x32x16_f16(                         \
                paP[kb], *(const half8*)(vb_ + offX[0][kb]), acc[0], 0, 0, 0);       \
            acc[1] = __builtin_amdgcn_mfma_f32_32x32x16_f16(                         \
                paP[kb], *(const half8*)(vb_ + offX[1][kb]), acc[1], 0, 0, 0);       \
            accl = __builtin_amdgcn_mfma_f32_32x32x16_f16(paP[kb], ones, accl, 0, 0, 0); \
        }                                                                            \
    }

#define SMAX_HALF(sc_, ks_)                                                          \
    {                                                                                \
        float p[16];                                                                 \
        _Pragma("unroll")                                                            \
        for (int r = 0; r < 16; r++) p[r] = __builtin_amdgcn_exp2f(sc_[r]);          \
        uint32_t u_[4][2];                                                           \
        _Pragma("unroll")                                                            \
        for (int c4 = 0; c4 < 4; c4++) {                                             \
            u_[c4][0] = pkrtz(p[4 * c4 + 0], p[4 * c4 + 1]);                         \
            u_[c4][1] = pkrtz(p[4 * c4 + 2], p[4 * c4 + 3]);                         \
        }                                                                            \
        _Pragma("unroll")                                                            \
        for (int mm = 0; mm < 2; mm++) {                                             \
            uint2v s0 = __builtin_amdgcn_permlane32_swap(                            \
                u_[2 * mm][0], u_[2 * mm + 1][0], false, false);                     \
            uint2v s1 = __builtin_amdgcn_permlane32_swap(                            \
                u_[2 * mm][1], u_[2 * mm + 1][1], false, false);                     \
            uintx4 w;                                                                \
            w[0] = s0[0]; w[1] = s1[0]; w[2] = s0[1]; w[3] = s1[1];                  \
            union { uintx4 u; half8 h; } cv; cv.u = w;                               \
            paP[(ks_) * 2 + mm] = cv.h;                                              \
        }                                                                            \
    }

    // prologue: stage tile 0 (K buf0, V buf A)
    STAGE_T(0, 0, 8192);
    __syncthreads();

    int vprev = 8192, vcurr = 8192 + 4096, vnext = 8192 + 8192;

    // peeled iter 0: stage tile 1; QK(0); softmax -> paP; no PV yet
    STAGE_T(64, 4096, vcurr);
    {
        floatx16 sc0, sc1;
        __builtin_amdgcn_s_setprio(1);
        QK_T(0);
        __builtin_amdgcn_s_setprio(0);
        SMAX_HALF(sc0, 0);
        SMAX_HALF(sc1, 1);
    }
    __syncthreads();

    for (int kt = 64; kt < LL; kt += 64) {   // t = 1..31
        const int cur = (kt >> 6) & 1;
        if (kt + 64 < LL) STAGE_T(kt + 64, (cur ^ 1) * 4096, vnext);

        floatx16 sc0, sc1;
        __builtin_amdgcn_s_setprio(1);
        QK_T(cur * 4096);      // 8 MFMA: S^T(t)
        PV_T(vprev);           // 12 MFMA: ctx += P(t-1).V^T(t-1), lsum += P(t-1).1
        __builtin_amdgcn_s_setprio(0);
        SMAX_HALF(sc0, 0);     // softmax(t) -> paP (overlaps other waves' MFMA)
        SMAX_HALF(sc1, 1);

        const int tr = vprev; vprev = vcurr; vcurr = vnext; vnext = tr;
        __syncthreads();
    }

    // final PV(31)
    __builtin_amdgcn_s_setprio(1);
    PV_T(vprev);
    __builtin_amdgcn_s_setprio(0);

#undef STAGE_T
#undef QK_T
#undef PV_T
#undef SMAX_HALF

    // ---- epilogue: ctx [B, L, E] fp32; accl[r] = lsum for this row ----
    #pragma unroll
    for (int r = 0; r < 16; r++) {
        const int qrow = (r & 3) + 8 * (r >> 2) + 4 * h2;
        const float iv = 1.f / accl[r];
        float* cp = ctx + ((size_t)b_ * LL + q0 + qrow) * EE + h_ * DD + l32;
        cp[0]  = acc[0][r] * iv;
        cp[32] = acc[1][r] * iv;
    }
}

// ---------------- launcher ----------------
extern "C" void kernel_launch(void* const* d_in, const int* in_sizes, int n_in,
                              void* d_out, int out_size, void* d_ws, size_t ws_size,
                              hipStream_t stream) {
    const float* query      = (const float*)d_in[0];
    const float* key        = (const float*)d_in[1];
    const float* value      = (const float*)d_in[2];
    const float* in_proj_w  = (const float*)d_in[3];
    const float* in_proj_b  = (const float*)d_in[4];
    const float* out_proj_w = (const float*)d_in[5];
    const float* out_proj_b = (const float*)d_in[6];
    float* out = (float*)d_out;

    char* ws = (char*)d_ws;
    double*   sums   = (double*)ws;                             // 32 B
    float*    scaleF = (float*)(ws + 32);                       // 16 B
    float*    gbuf   = (float*)(ws + 256);                      // 4*TT floats
    int8_t*   qw8    = (int8_t*)(ws + (size_t)1  * 1024 * 1024);  // 4 MB ternary i8
    int8_t*   qx8    = (int8_t*)(ws + (size_t)8  * 1024 * 1024);  // 4 slabs x 8 MB
    _Float16* Qh     = (_Float16*)(ws + (size_t)40 * 1024 * 1024); // 3 slabs x 16 MB
    _Float16* Kh     = Qh + (size_t)TT * EE;
    _Float16* Vth    = Kh + (size_t)TT * EE;                    // V^T [B,H,D,L]
    float*    ctx    = out;   // d_out doubles as fp32 ctx scratch (fully overwritten)

    const float QPRE = 0.18033688011112042f;  // (1/8) * log2(e)

    hipMemsetAsync(sums, 0, 32, stream);
    k_absum<<<dim3(256, 4), 256, 0, stream>>>(in_proj_w, out_proj_w, sums);
    k_quantw<<<(4 * EE * EE) / 256, 256, 0, stream>>>(in_proj_w, out_proj_w, sums, scaleF, qw8);
    k_gammaq3<<<dim3(TT / 4, 3), 256, 0, stream>>>(query, key, value, gbuf, qx8);

    // fused Q/K/V^T projections (1-D XCD-swizzled grid, 64x8x3 blocks)
    k_bitmm<<<dim3(64 * 8 * 3), 256, 0, stream>>>(
        qx8, gbuf, qw8, scaleF, in_proj_b, out_proj_b, nullptr, Qh, 0, QPRE);

    k_attn5<<<dim3((LL / 128) * BB * HH), 256, 0, stream>>>(Qh, Kh, Vth, ctx);

    // requantize ctx (slab 3) + out-projection (1-D XCD-swizzled grid, 64x8 blocks)
    k_gammaq<<<TT / 4, 256, 0, stream>>>(ctx, gbuf + 3 * TT, qx8 + 3 * (size_t)TT * EE);
    k_bitmm<<<dim3(64 * 8), 256, 0, stream>>>(
        qx8, gbuf, qw8, scaleF, in_proj_b, out_proj_b, out, Qh, 3, QPRE);
}